// Round 2
// baseline (1491.982 us; speedup 1.0000x reference)
//
#include <hip/hip_runtime.h>
#include <hip/hip_bf16.h>
#include <math.h>

#define WW     160
#define NBATCH 4
#define VOL    (160*160*160)      // 4,096,000
#define PLANE  (160*160)

#define C1f 0.0001f
#define C2f 0.0009f

#define RUN_H 40   // h outputs per block in pass A (reads RUN_H+10 rows)
#define RUN_D 40   // d outputs per block in pass B (reads RUN_D+10 slices)

struct Gw { float g[11]; };

// ---------------- Pass A: W-conv + H-conv fused, streaming h ----------------
// block 192 threads (3 waves), lane = w (active w<160)
// grid (160/RUN_H, d=160, batch=4) = 2560 blocks
__global__ __launch_bounds__(192) void k_wh(
    const float* __restrict__ x, const float* __restrict__ y,
    __hip_bfloat16* __restrict__ B, Gw gw)
{
    __shared__ float2 srow[176];            // index w+5; 171 used
    const int t  = threadIdx.x;
    const int w  = t;
    const int h0 = blockIdx.x * RUN_H;
    const int d  = blockIdx.y;
    const int n  = blockIdx.z;

    const float* xb = x + (size_t)n * VOL + (size_t)d * PLANE;
    const float* yb = y + (size_t)n * VOL + (size_t)d * PLANE;
    __hip_bfloat16* Bb = B + (size_t)n * 5 * VOL + (size_t)d * PLANE;

    float ring[5][11];

    // preload row i=0 (h = h0-5) into registers
    float px = 0.f, py = 0.f;
    {
        int h = h0 - 5, wc = t - 5;
        if (t < 171 && h >= 0 && h < 160 && wc >= 0 && wc < 160) {
            px = xb[(size_t)h * WW + wc];
            py = yb[(size_t)h * WW + wc];
        }
    }

#pragma unroll
    for (int i = 0; i < RUN_H + 10; ++i) {
        __syncthreads();                    // prior readers done before overwrite
        if (t < 171) srow[t] = make_float2(px, py);
        // issue next row's global loads early (hidden under compute below)
        px = 0.f; py = 0.f;
        if (i + 1 < RUN_H + 10) {
            int h = h0 - 5 + i + 1, wc = t - 5;
            if (t < 171 && h >= 0 && h < 160 && wc >= 0 && wc < 160) {
                px = xb[(size_t)h * WW + wc];
                py = yb[(size_t)h * WW + wc];
            }
        }
        __syncthreads();                    // srow ready

        if (w < 160) {
            float a0=0.f,a1=0.f,a2=0.f,a3=0.f,a4=0.f;
#pragma unroll
            for (int k = 0; k < 11; ++k) {
                float2 v = srow[w + k];
                float g = gw.g[k];
                a0 += g * v.x;
                a1 += g * v.y;
                a2 += g * (v.x * v.x);
                a3 += g * (v.y * v.y);
                a4 += g * (v.x * v.y);
            }
            ring[0][i%11]=a0; ring[1][i%11]=a1; ring[2][i%11]=a2;
            ring[3][i%11]=a3; ring[4][i%11]=a4;

            if (i >= 10) {
                const int j = i - 10;       // output row h0+j
                float o[5] = {0.f,0.f,0.f,0.f,0.f};
#pragma unroll
                for (int k = 0; k < 11; ++k) {
                    float g = gw.g[k];
#pragma unroll
                    for (int c = 0; c < 5; ++c)
                        o[c] += g * ring[c][(j + k) % 11];
                }
                size_t oi = (size_t)(h0 + j) * WW + w;
#pragma unroll
                for (int c = 0; c < 5; ++c)
                    Bb[oi + (size_t)c * VOL] = __float2bfloat16(o[c]);
            }
        }
    }
}

// ---------------- Pass B: D-conv + SSIM + reduction ----------------
// block 192 threads (3 waves), lane = w; grid (160/RUN_D, h=160, batch=4) = 2560 blocks
__global__ __launch_bounds__(192) void k_dssim(
    const __hip_bfloat16* __restrict__ B, double* __restrict__ accum, Gw gw)
{
    const int w  = threadIdx.x;
    const int d0 = blockIdx.x * RUN_D;
    const int h  = blockIdx.y;
    const int n  = blockIdx.z;

    float lsum = 0.f;
    if (w < 160) {
        const __hip_bfloat16* Bb = B + (size_t)n * 5 * VOL + (size_t)h * WW + w;
        float ring[5][11];
        float cur[5];
        {
            int dd = d0 - 5;
            bool ok = (dd >= 0) && (dd < 160);
#pragma unroll
            for (int c = 0; c < 5; ++c)
                cur[c] = ok ? __bfloat162float(Bb[(size_t)dd * PLANE + (size_t)c * VOL]) : 0.f;
        }
#pragma unroll
        for (int i = 0; i < RUN_D + 10; ++i) {
#pragma unroll
            for (int c = 0; c < 5; ++c) ring[c][i % 11] = cur[c];
            // prefetch next slice early
            if (i + 1 < RUN_D + 10) {
                int dd = d0 - 5 + i + 1;
                bool ok = (dd >= 0) && (dd < 160);
#pragma unroll
                for (int c = 0; c < 5; ++c)
                    cur[c] = ok ? __bfloat162float(Bb[(size_t)dd * PLANE + (size_t)c * VOL]) : 0.f;
            }
            if (i >= 10) {
                const int j = i - 10;
                float o[5] = {0.f,0.f,0.f,0.f,0.f};
#pragma unroll
                for (int k = 0; k < 11; ++k) {
                    float g = gw.g[k];
#pragma unroll
                    for (int c = 0; c < 5; ++c)
                        o[c] += g * ring[c][(j + k) % 11];
                }
                float mu1 = o[0], mu2 = o[1];
                float e11 = o[2], e22 = o[3], e12 = o[4];
                float m11 = mu1 * mu2;
                float num = (2.f * m11 + C1f) * (2.f * (e12 - m11) + C2f);
                float den = (mu1 * mu1 + mu2 * mu2 + C1f) *
                            ((e11 - mu1 * mu1) + (e22 - mu2 * mu2) + C2f);
                lsum += num / den;
            }
        }
    }
    // wave reduce (3 waves) then block reduce then one atomic
    __shared__ float wsum[3];
#pragma unroll
    for (int off = 32; off > 0; off >>= 1)
        lsum += __shfl_down(lsum, off, 64);
    const int lane = threadIdx.x & 63, wid = threadIdx.x >> 6;
    if (lane == 0) wsum[wid] = lsum;
    __syncthreads();
    if (threadIdx.x == 0)
        atomicAdd(accum, (double)(wsum[0] + wsum[1] + wsum[2]));
}

__global__ void k_final(const double* __restrict__ accum, float* __restrict__ out)
{
    out[0] = (float)(1.0 - accum[0] / ((double)NBATCH * (double)VOL));
}

extern "C" void kernel_launch(void* const* d_in, const int* in_sizes, int n_in,
                              void* d_out, int out_size, void* d_ws, size_t ws_size,
                              hipStream_t stream)
{
    const float* img1 = (const float*)d_in[0];
    const float* img2 = (const float*)d_in[1];
    float* out = (float*)d_out;

    char* ws = (char*)d_ws;
    __hip_bfloat16* B = (__hip_bfloat16*)ws;                 // 5*VOL*NBATCH bf16 = 163.84 MB
    double* accum = (double*)(ws + (size_t)5 * VOL * NBATCH * sizeof(__hip_bfloat16));

    Gw gw;
    {
        double gd[11], s = 0.0;
        for (int i = 0; i < 11; ++i) {
            double t = (double)(i - 5);
            gd[i] = exp(-(t * t) / (2.0 * 1.5 * 1.5));
            s += gd[i];
        }
        for (int i = 0; i < 11; ++i) gw.g[i] = (float)(gd[i] / s);
    }

    hipMemsetAsync(accum, 0, sizeof(double), stream);

    k_wh   <<<dim3(160 / RUN_H, 160, NBATCH), 192, 0, stream>>>(img1, img2, B, gw);
    k_dssim<<<dim3(160 / RUN_D, 160, NBATCH), 192, 0, stream>>>(B, accum, gw);
    k_final<<<1, 1, 0, stream>>>(accum, out);
}

// Round 3
// 635.738 us; speedup vs baseline: 2.3468x; 2.3468x over previous
//
#include <hip/hip_runtime.h>
#include <math.h>

#define WW     160
#define NBATCH 4
#define VOL    (160*160*160)      // 4,096,000
#define PLANE  (160*160)

#define C1f 0.0001f
#define C2f 0.0009f

#define RUN_H 20   // h outputs per k_wh block (reads RUN_H+10 rows)
#define RUN_D 20   // d outputs per k_dssim block (reads RUN_D+10 slices)

struct Gw { float g[11]; };

// ---------------- Pass A: W-conv + H-conv fused, fp32, 1 wave/block ----------------
// block 64 (lane = w within 64-wide chunk); grid (3 wchunks, 160/RUN_H, d=160)
__global__ __launch_bounds__(64) void k_wh(
    const float* __restrict__ x, const float* __restrict__ y,
    float* __restrict__ B, Gw gw)
{
    __shared__ float sx[80];
    __shared__ float sy[80];
    const int lane = threadIdx.x;
    const int w0   = blockIdx.x * 64;
    const int h0   = blockIdx.y * RUN_H;
    const int d    = blockIdx.z;
    const int w    = w0 + lane;

    const float* xb = x + (size_t)d * PLANE;
    const float* yb = y + (size_t)d * PLANE;
    float*       Bb = B + (size_t)d * PLANE;

    float ring[5][11];

#pragma unroll
    for (int i = 0; i < RUN_H + 10; ++i) {
        const int h   = h0 - 5 + i;
        const bool hok = (h >= 0) && (h < 160);
        const int hc  = hok ? h : 0;
        const float* xr = xb + (size_t)hc * WW;
        const float* yr = yb + (size_t)hc * WW;

        // stage 74 floats (w0-5 .. w0+68) per array; single wave -> barrier cheap
        {
            int g0 = w0 - 5 + lane;               // t = lane
            bool ok0 = hok && (g0 >= 0) && (g0 < 160);
            float vx0 = ok0 ? xr[ok0 ? g0 : 0] : 0.f;
            float vy0 = ok0 ? yr[ok0 ? g0 : 0] : 0.f;
            int t1 = lane + 64;                   // t = lane+64 (only t<74 meaningful)
            int g1 = w0 + 59 + lane;              // >= 0 always
            bool ok1 = hok && (t1 < 74) && (g1 < 160);
            float vx1 = ok1 ? xr[ok1 ? g1 : 0] : 0.f;
            float vy1 = ok1 ? yr[ok1 ? g1 : 0] : 0.f;
            __syncthreads();                      // protect WAR vs previous iter (1-wave: cheap)
            sx[lane] = vx0;  sy[lane] = vy0;
            if (t1 < 80) { sx[t1] = vx1; sy[t1] = vy1; }
            __syncthreads();
        }

        float a0=0.f,a1=0.f,a2=0.f,a3=0.f,a4=0.f;
#pragma unroll
        for (int k = 0; k < 11; ++k) {
            float xa = sx[lane + k];
            float ya = sy[lane + k];
            float g  = gw.g[k];
            a0 += g * xa;
            a1 += g * ya;
            a2 += g * (xa * xa);
            a3 += g * (ya * ya);
            a4 += g * (xa * ya);
        }
        ring[0][i%11]=a0; ring[1][i%11]=a1; ring[2][i%11]=a2;
        ring[3][i%11]=a3; ring[4][i%11]=a4;

        if (i >= 10 && w < 160) {
            const int j = i - 10;                 // output row h0+j
            float o[5] = {0.f,0.f,0.f,0.f,0.f};
#pragma unroll
            for (int k = 0; k < 11; ++k) {
                float g = gw.g[k];
#pragma unroll
                for (int c = 0; c < 5; ++c)
                    o[c] += g * ring[c][(j + k) % 11];
            }
            size_t oi = (size_t)(h0 + j) * WW + w;
#pragma unroll
            for (int c = 0; c < 5; ++c)
                Bb[oi + (size_t)c * VOL] = o[c];
        }
    }
}

// ---------------- Pass B: D-conv + SSIM + reduction (R1-proven structure) ----------------
// block 64 (lane = w within chunk); grid (3 wchunks, h=160, 160/RUN_D)
__global__ __launch_bounds__(64) void k_dssim(
    const float* __restrict__ B, double* __restrict__ accum, Gw gw)
{
    const int lane = threadIdx.x;
    const int w  = blockIdx.x * 64 + lane;
    const int h  = blockIdx.y;
    const int d0 = blockIdx.z * RUN_D;

    float lsum = 0.f;
    if (w < 160) {
        const float* base = B + (size_t)h * WW + w;
        float ring[5][11];
#pragma unroll
        for (int i = 0; i < RUN_D + 10; ++i) {
            int dd = d0 - 5 + i;
            bool ok = (dd >= 0) && (dd < 160);
            int dc = ok ? dd : 0;
            size_t idx = (size_t)dc * PLANE;
#pragma unroll
            for (int c = 0; c < 5; ++c) {
                float v = base[idx + (size_t)c * VOL];
                ring[c][i % 11] = ok ? v : 0.f;
            }
            if (i >= 10) {
                const int j = i - 10;
                float o[5] = {0.f,0.f,0.f,0.f,0.f};
#pragma unroll
                for (int k = 0; k < 11; ++k) {
                    float g = gw.g[k];
#pragma unroll
                    for (int c = 0; c < 5; ++c)
                        o[c] += g * ring[c][(j + k) % 11];
                }
                float mu1 = o[0], mu2 = o[1];
                float e11 = o[2], e22 = o[3], e12 = o[4];
                float m11 = mu1 * mu2;
                float num = (2.f * m11 + C1f) * (2.f * (e12 - m11) + C2f);
                float den = (mu1 * mu1 + mu2 * mu2 + C1f) *
                            ((e11 - mu1 * mu1) + (e22 - mu2 * mu2) + C2f);
                lsum += num / den;
            }
        }
    }
    // wave64 reduction, one atomic per block
#pragma unroll
    for (int off = 32; off > 0; off >>= 1)
        lsum += __shfl_down(lsum, off, 64);
    if (lane == 0)
        atomicAdd(accum, (double)lsum);
}

__global__ void k_final(const double* __restrict__ accum, float* __restrict__ out)
{
    out[0] = (float)(1.0 - accum[0] / ((double)NBATCH * (double)VOL));
}

extern "C" void kernel_launch(void* const* d_in, const int* in_sizes, int n_in,
                              void* d_out, int out_size, void* d_ws, size_t ws_size,
                              hipStream_t stream)
{
    const float* img1 = (const float*)d_in[0];
    const float* img2 = (const float*)d_in[1];
    float* out = (float*)d_out;

    char* ws = (char*)d_ws;
    float* B = (float*)ws;                                  // 5*VOL fp32 = 81.92 MB (per-batch reuse)
    double* accum = (double*)(ws + (size_t)5 * VOL * sizeof(float));

    Gw gw;
    {
        double gd[11], s = 0.0;
        for (int i = 0; i < 11; ++i) {
            double t = (double)(i - 5);
            gd[i] = exp(-(t * t) / (2.0 * 1.5 * 1.5));
            s += gd[i];
        }
        for (int i = 0; i < 11; ++i) gw.g[i] = (float)(gd[i] / s);
    }

    hipMemsetAsync(accum, 0, sizeof(double), stream);

    for (int n = 0; n < NBATCH; ++n) {
        const float* xn = img1 + (size_t)n * VOL;
        const float* yn = img2 + (size_t)n * VOL;
        k_wh   <<<dim3(3, 160 / RUN_H, 160), 64, 0, stream>>>(xn, yn, B, gw);
        k_dssim<<<dim3(3, 160, 160 / RUN_D), 64, 0, stream>>>(B, accum, gw);
    }
    k_final<<<1, 1, 0, stream>>>(accum, out);
}

// Round 4
// 465.290 us; speedup vs baseline: 3.2066x; 1.3663x over previous
//
#include <hip/hip_runtime.h>
#include <math.h>

#define WW     160
#define NBATCH 4
#define VOL    (160*160*160)      // 4,096,000
#define PLANE  (160*160)

#define C1f 0.0001f
#define C2f 0.0009f

#define RUN_H 16                  // h outputs per k_wh block
#define NROWS (RUN_H + 10)        // 26 rows staged
#define LDW   176                 // padded cols: [0..4]=0, [5..164]=data, [165..175]=0
#define RUN_D 20                  // d outputs per k_dssim block

struct Gw { float g[11]; };

// ---------------- Pass A: W+H conv fused; one-shot LDS tile, 1 barrier ----------------
// block 192 (3 waves; threads 0..159 compute, all 192 load); grid (160/RUN_H, d=160)
__global__ __launch_bounds__(192) void k_wh(
    const float* __restrict__ x, const float* __restrict__ y,
    float* __restrict__ B, Gw gw)
{
    __shared__ float2 tile[NROWS][LDW];    // 26*176*8 = 36.6 KB
    const int t  = threadIdx.x;
    const int h0 = blockIdx.x * RUN_H;
    const int d  = blockIdx.y;

    const float* xb = x + (size_t)d * PLANE;
    const float* yb = y + (size_t)d * PLANE;

    // ---- fill tile: ~24 slots/thread, all loads independent (deep MLP) ----
#pragma unroll 4
    for (int s = t; s < NROWS * LDW; s += 192) {
        int r = s / LDW, c = s - r * LDW;
        int h = h0 - 5 + r;
        int w = c - 5;
        float vx = 0.f, vy = 0.f;
        if (h >= 0 && h < 160 && w >= 0 && w < 160) {
            size_t idx = (size_t)h * WW + w;
            vx = xb[idx];
            vy = yb[idx];
        }
        tile[r][c] = make_float2(vx, vy);
    }
    __syncthreads();

    // ---- compute: pure LDS + VALU, no global dependency ----
    if (t < 160) {
        const int w = t;
        float* Bb = B + (size_t)d * PLANE + w;
        float ring[5][11];
#pragma unroll
        for (int i = 0; i < NROWS; ++i) {
            float a0=0.f,a1=0.f,a2=0.f,a3=0.f,a4=0.f;
#pragma unroll
            for (int k = 0; k < 11; ++k) {
                float2 v = tile[i][w + k];     // input w-5+k
                float g = gw.g[k];
                a0 += g * v.x;
                a1 += g * v.y;
                a2 += g * (v.x * v.x);
                a3 += g * (v.y * v.y);
                a4 += g * (v.x * v.y);
            }
            ring[0][i%11]=a0; ring[1][i%11]=a1; ring[2][i%11]=a2;
            ring[3][i%11]=a3; ring[4][i%11]=a4;

            if (i >= 10) {
                const int j = i - 10;          // output row h0+j
                float o[5] = {0.f,0.f,0.f,0.f,0.f};
#pragma unroll
                for (int k = 0; k < 11; ++k) {
                    float g = gw.g[k];
#pragma unroll
                    for (int c = 0; c < 5; ++c)
                        o[c] += g * ring[c][(j + k) % 11];
                }
                size_t oi = (size_t)(h0 + j) * WW;
#pragma unroll
                for (int c = 0; c < 5; ++c)
                    Bb[oi + (size_t)c * VOL] = o[c];
            }
        }
    }
}

// ---------------- Pass B: D-conv + SSIM; 4 waves/block, register prefetch ----------------
// block 256 (wave wi -> h = by*4+wi, lanes -> w chunk); grid (3, 40, 160/RUN_D)
__global__ __launch_bounds__(256) void k_dssim(
    const float* __restrict__ B, double* __restrict__ accum, Gw gw)
{
    const int lane = threadIdx.x & 63;
    const int wi   = threadIdx.x >> 6;
    const int w    = blockIdx.x * 64 + lane;
    const int h    = blockIdx.y * 4 + wi;
    const int d0   = blockIdx.z * RUN_D;

    float lsum = 0.f;
    if (w < 160) {
        const float* base = B + (size_t)h * WW + w;
        float ring[5][11];
        float cur[5];
        {   // prefetch i=0 (d = d0-5)
            int dd = d0 - 5;
            bool ok = (dd >= 0) && (dd < 160);
            size_t idx = (size_t)(ok ? dd : 0) * PLANE;
#pragma unroll
            for (int c = 0; c < 5; ++c) {
                float v = base[idx + (size_t)c * VOL];
                cur[c] = ok ? v : 0.f;
            }
        }
#pragma unroll
        for (int i = 0; i < RUN_D + 10; ++i) {
#pragma unroll
            for (int c = 0; c < 5; ++c) ring[c][i % 11] = cur[c];
            // issue next slice's 5 loads now; consumed next iteration
            if (i + 1 < RUN_D + 10) {
                int dd = d0 - 5 + i + 1;
                bool ok = (dd >= 0) && (dd < 160);
                size_t idx = (size_t)(ok ? dd : 0) * PLANE;
#pragma unroll
                for (int c = 0; c < 5; ++c) {
                    float v = base[idx + (size_t)c * VOL];
                    cur[c] = ok ? v : 0.f;
                }
            }
            if (i >= 10) {
                const int j = i - 10;
                float o[5] = {0.f,0.f,0.f,0.f,0.f};
#pragma unroll
                for (int k = 0; k < 11; ++k) {
                    float g = gw.g[k];
#pragma unroll
                    for (int c = 0; c < 5; ++c)
                        o[c] += g * ring[c][(j + k) % 11];
                }
                float mu1 = o[0], mu2 = o[1];
                float e11 = o[2], e22 = o[3], e12 = o[4];
                float m11 = mu1 * mu2;
                float num = (2.f * m11 + C1f) * (2.f * (e12 - m11) + C2f);
                float den = (mu1 * mu1 + mu2 * mu2 + C1f) *
                            ((e11 - mu1 * mu1) + (e22 - mu2 * mu2) + C2f);
                lsum += num / den;
            }
        }
    }
    // wave reduce then block reduce, one atomic per block
    __shared__ float wsum[4];
#pragma unroll
    for (int off = 32; off > 0; off >>= 1)
        lsum += __shfl_down(lsum, off, 64);
    if (lane == 0) wsum[wi] = lsum;
    __syncthreads();
    if (threadIdx.x == 0)
        atomicAdd(accum, (double)(wsum[0] + wsum[1] + wsum[2] + wsum[3]));
}

__global__ void k_final(const double* __restrict__ accum, float* __restrict__ out)
{
    out[0] = (float)(1.0 - accum[0] / ((double)NBATCH * (double)VOL));
}

extern "C" void kernel_launch(void* const* d_in, const int* in_sizes, int n_in,
                              void* d_out, int out_size, void* d_ws, size_t ws_size,
                              hipStream_t stream)
{
    const float* img1 = (const float*)d_in[0];
    const float* img2 = (const float*)d_in[1];
    float* out = (float*)d_out;

    char* ws = (char*)d_ws;
    float* B = (float*)ws;                                  // 5*VOL fp32 = 81.92 MB (per-batch reuse)
    double* accum = (double*)(ws + (size_t)5 * VOL * sizeof(float));

    Gw gw;
    {
        double gd[11], s = 0.0;
        for (int i = 0; i < 11; ++i) {
            double t = (double)(i - 5);
            gd[i] = exp(-(t * t) / (2.0 * 1.5 * 1.5));
            s += gd[i];
        }
        for (int i = 0; i < 11; ++i) gw.g[i] = (float)(gd[i] / s);
    }

    hipMemsetAsync(accum, 0, sizeof(double), stream);

    for (int n = 0; n < NBATCH; ++n) {
        const float* xn = img1 + (size_t)n * VOL;
        const float* yn = img2 + (size_t)n * VOL;
        k_wh   <<<dim3(160 / RUN_H, 160), 192, 0, stream>>>(xn, yn, B, gw);
        k_dssim<<<dim3(3, 40, 160 / RUN_D), 256, 0, stream>>>(B, accum, gw);
    }
    k_final<<<1, 1, 0, stream>>>(accum, out);
}